// Round 13
// baseline (2097.445 us; speedup 1.0000x reference)
//
#include <hip/hip_runtime.h>
#include <math.h>

#define N_NODES 100000
#define N_EDGES 3200000
#define IN_CH 32
#define HID 64
#define NPB 128                                   // dst nodes per bucket/gather-block
#define NBK ((N_NODES + NPB - 1) / NPB)           // 782
#define CAP 4608                                  // bucket capacity (mean 4096 + 8 sigma)
#define NTILE 7                                   // src>>14 : 0..6
#define PCHUNK 16384                              // edges per partition block
#define PBLOCKS ((N_EDGES + PCHUNK - 1) / PCHUNK) // 196
#define ST1 33                                    // LDS acc row stride, layer 1 (odd)
#define ST2 65                                    // LDS acc row stride, layer 2 (odd)

typedef unsigned short ushort_t;
typedef unsigned long long u64_t;

// ---------------- bf16 helpers ----------------
__device__ __forceinline__ float bflo(unsigned u) { return __uint_as_float(u << 16); }
__device__ __forceinline__ float bfhi(unsigned u) { return __uint_as_float(u & 0xffff0000u); }
__device__ __forceinline__ unsigned packbf(float a, float b) {
    unsigned ua = __float_as_uint(a); ua += 0x7fffu + ((ua >> 16) & 1u);
    unsigned ub = __float_as_uint(b); ub += 0x7fffu + ((ub >> 16) & 1u);
    return (ua >> 16) | (ub & 0xffff0000u);
}

// ---------------------------------------------------------------------------
// K1: partition edges into fixed-capacity bucket regions (bucket = dst>>7).
// Payload: u = src | local_dst<<17   (src < 2^17, local_dst < 128)
// ---------------------------------------------------------------------------
__global__ void partition_kernel(const int* __restrict__ src, const int* __restrict__ dst,
                                 int* __restrict__ gcursor, int* __restrict__ gsw) {
    __shared__ int h[NBK], lbase[NBK], lcur[NBK];
    int t = threadIdx.x;
    for (int i = t; i < NBK; i += 256) { h[i] = 0; lcur[i] = 0; }
    __syncthreads();
    const int4* d4 = (const int4*)dst;
    const int4* s4 = (const int4*)src;
    int i0 = blockIdx.x * (PCHUNK / 4) + t;
#pragma unroll
    for (int j = 0; j < PCHUNK / 1024; ++j) {
        int i4 = i0 + j * 256;
        if (i4 < N_EDGES / 4) {
            int4 d = d4[i4];
            atomicAdd(&h[d.x >> 7], 1);
            atomicAdd(&h[d.y >> 7], 1);
            atomicAdd(&h[d.z >> 7], 1);
            atomicAdd(&h[d.w >> 7], 1);
        }
    }
    __syncthreads();
    for (int i = t; i < NBK; i += 256)
        lbase[i] = h[i] ? atomicAdd(&gcursor[i], h[i]) : 0;
    __syncthreads();
#pragma unroll
    for (int j = 0; j < PCHUNK / 1024; ++j) {
        int i4 = i0 + j * 256;
        if (i4 < N_EDGES / 4) {
            int4 d = d4[i4];
            int4 s = s4[i4];
            int b, r, idx;
            b = d.x >> 7; r = atomicAdd(&lcur[b], 1); idx = lbase[b] + r;
            if (idx < CAP) gsw[(size_t)b * CAP + idx] = s.x | ((d.x & (NPB - 1)) << 17);
            b = d.y >> 7; r = atomicAdd(&lcur[b], 1); idx = lbase[b] + r;
            if (idx < CAP) gsw[(size_t)b * CAP + idx] = s.y | ((d.y & (NPB - 1)) << 17);
            b = d.z >> 7; r = atomicAdd(&lcur[b], 1); idx = lbase[b] + r;
            if (idx < CAP) gsw[(size_t)b * CAP + idx] = s.z | ((d.z & (NPB - 1)) << 17);
            b = d.w >> 7; r = atomicAdd(&lcur[b], 1); idx = lbase[b] + r;
            if (idx < CAP) gsw[(size_t)b * CAP + idx] = s.w | ((d.w & (NPB - 1)) << 17);
        }
    }
}

// ---------------------------------------------------------------------------
// K2: per-bucket compaction, sorted by (src-tile, local_dst). Outputs:
//   esw (payload src|ld<<17), bbase[k], bcnt[k], dinv, fused Xs = X*dinv bf16.
// ---------------------------------------------------------------------------
__global__ __launch_bounds__(1024) void bucket_place_kernel(
        const int* __restrict__ gsw, const int* __restrict__ gcursor,
        const float* __restrict__ X,
        int* __restrict__ bbase, int* __restrict__ bcnt, float* __restrict__ dinv,
        int* __restrict__ esw, ushort_t* __restrict__ Xs) {
    __shared__ int cnt[8 * NPB], cur[8 * NPB], exc[8 * NPB];
    __shared__ int sa[1024], sb[1024];
    __shared__ int red[1024];
    __shared__ float dl[NPB];
    int t = threadIdx.x;
    int k = blockIdx.x;
    int d0 = k * NPB;
    cnt[t] = 0; cur[t] = 0;
    // cbase = sum of min(gcursor[j], CAP) over j < k
    int local = 0;
    for (int i = t; i < k; i += 1024) local += min(gcursor[i], CAP);
    red[t] = local;
    __syncthreads();
    for (int off = 512; off > 0; off >>= 1) {
        if (t < off) red[t] += red[t + off];
        __syncthreads();
    }
    int cbase = red[0];
    int total = min(gcursor[k], CAP);
    const int* reg = gsw + (size_t)k * CAP;
    // pass 1: count per (tile, ld)
    for (int i = t; i < total; i += 1024) {
        int u = reg[i];
        atomicAdd(&cnt[((u & 0x1FFFF) >> 14) * NPB + (u >> 17)], 1);
    }
    __syncthreads();
    // per-node degree -> dinv
    if (t < NPB) {
        int deg = 0;
#pragma unroll
        for (int tt = 0; tt < NTILE; ++tt) deg += cnt[tt * NPB + t];
        float di = rsqrtf((float)deg + 1.0f);
        dl[t] = di;
        if (d0 + t < N_NODES) dinv[d0 + t] = di;
    }
    // exclusive scan over the 896 (tile, ld) slots
    sa[t] = (t < NTILE * NPB) ? cnt[t] : 0;
    __syncthreads();
    int* pa = sa; int* pb = sb;
    for (int off = 1; off < 1024; off <<= 1) {
        int add = (t >= off) ? pa[t - off] : 0;
        pb[t] = pa[t] + add;
        __syncthreads();
        int* tmp = pa; pa = pb; pb = tmp;
    }
    if (t < NTILE * NPB) exc[t] = pa[t] - cnt[t];
    if (t == 0) { bbase[k] = cbase; bcnt[k] = total; }
    __syncthreads();
    // pass 2: place
    for (int i = t; i < total; i += 1024) {
        int u = reg[i];
        int li = ((u & 0x1FFFF) >> 14) * NPB + (u >> 17);
        int r = atomicAdd(&cur[li], 1);
        esw[cbase + exc[li] + r] = u;
    }
    // fused Xs = X * dinv for this bucket's nodes
    const float4* X4 = (const float4*)X;
    for (int i = t; i < NPB * 8; i += 1024) {
        int nl = i >> 3;
        int node = d0 + nl;
        if (node >= N_NODES) break;
        float di = dl[nl];
        float4 v = X4[(size_t)node * 8 + (i & 7)];
        u64_t o = ((u64_t)packbf(v.z * di, v.w * di) << 32) | packbf(v.x * di, v.y * di);
        *(u64_t*)((uint2*)Xs + (size_t)node * 8 + (i & 7)) = o;
    }
}

// ---------------------------------------------------------------------------
// K3: layer-1 edge-flow gather (32 ch). Block k owns nodes [k*128, k*128+128).
// 32 groups x 8 lanes; group G processes edges G, G+32, ... of the block run
// (tile-sorted -> cross-block L2 phase locking). ds_add_f32 into acc[128][33].
//   y[d] = dinv[d] * (sum_e Xs[src_e] + Xs[d])  -> bf16 [N][32]
// ---------------------------------------------------------------------------
__global__ __launch_bounds__(256) void gather1_flow_kernel(
        const int* __restrict__ esw, const int* __restrict__ bbase,
        const int* __restrict__ bcnt, const float* __restrict__ dinv,
        const ushort_t* __restrict__ Xs, ushort_t* __restrict__ y) {
    __shared__ float acc[NPB * ST1];
    int t = threadIdx.x;
    for (int i = t; i < NPB * ST1; i += 256) acc[i] = 0.f;
    __syncthreads();
    int k = blockIdx.x;
    int w = t >> 6, lane = t & 63;
    int q = lane >> 3, s = lane & 7;
    int G = w + 4 * q;                 // 0..31, in-wave concurrent groups spaced 4
    int beg = bbase[k], ecnt = bcnt[k];
    const uint2* H8 = (const uint2*)Xs;
    for (int i = G; i < ecnt; i += 32) {
        int u = esw[beg + i];
        int sv = u & 0x1FFFF;
        int ld = u >> 17;
        uint2 v = H8[(size_t)sv * 8 + s];
        float* ap = &acc[ld * ST1 + s * 4];
        atomicAdd(ap + 0, bflo(v.x));
        atomicAdd(ap + 1, bfhi(v.x));
        atomicAdd(ap + 2, bflo(v.y));
        atomicAdd(ap + 3, bfhi(v.y));
    }
    __syncthreads();
    // finalize: 256 threads = 128 nodes x 2 halves (16 ch each)
    int ln = t >> 1, half = t & 1;
    int node = k * NPB + ln;
    if (node >= N_NODES) return;
    float di = dinv[node];
    const float* ap = &acc[ln * ST1 + half * 16];
#pragma unroll
    for (int j = 0; j < 4; ++j) {
        uint2 hn = H8[(size_t)node * 8 + half * 4 + j];
        float r0 = di * (ap[j * 4 + 0] + bflo(hn.x));
        float r1 = di * (ap[j * 4 + 1] + bfhi(hn.x));
        float r2 = di * (ap[j * 4 + 2] + bflo(hn.y));
        float r3 = di * (ap[j * 4 + 3] + bfhi(hn.y));
        u64_t o = ((u64_t)packbf(r2, r3) << 32) | packbf(r0, r1);
        *(u64_t*)((uint2*)y + (size_t)node * 8 + half * 4 + j) = o;
    }
}

// ---------------------------------------------------------------------------
// K4: fused dense: H1 = relu(y@W1 + b1); Hs2 = (H1@W2)*dinv -> bf16 [N][64]
// ---------------------------------------------------------------------------
__global__ __launch_bounds__(256) void dense12_kernel(
        const ushort_t* __restrict__ ybf, const float* __restrict__ W1,
        const float* __restrict__ b1, const float* __restrict__ W2,
        const float* __restrict__ dinv, ushort_t* __restrict__ Hs2) {
    __shared__ float W1l[IN_CH * HID];
    __shared__ float W2l[HID * HID];
    __shared__ float Yl[32 * IN_CH];
    __shared__ float H1l[32 * HID];
    int t = threadIdx.x;
    int node0 = blockIdx.x * 32;
    for (int i = t; i < IN_CH * HID / 4; i += 256) ((float4*)W1l)[i] = ((const float4*)W1)[i];
    for (int i = t; i < HID * HID / 4; i += 256) ((float4*)W2l)[i] = ((const float4*)W2)[i];
    {
        uint2 v = ((const uint2*)ybf)[(size_t)node0 * 8 + t];
        int nl = t >> 3, ci = t & 7;
        Yl[nl * IN_CH + ci * 4 + 0] = bflo(v.x);
        Yl[nl * IN_CH + ci * 4 + 1] = bfhi(v.x);
        Yl[nl * IN_CH + ci * 4 + 2] = bflo(v.y);
        Yl[nl * IN_CH + ci * 4 + 3] = bfhi(v.y);
    }
    __syncthreads();
    int nl = t >> 3;
    int c8 = t & 7;
    int ch0 = c8 * 8;
    float4 bA = ((const float4*)b1)[c8 * 2];
    float4 bB = ((const float4*)b1)[c8 * 2 + 1];
    float a0 = bA.x, a1 = bA.y, a2 = bA.z, a3 = bA.w;
    float a4 = bB.x, a5 = bB.y, a6 = bB.z, a7 = bB.w;
#pragma unroll
    for (int kk = 0; kk < IN_CH; ++kk) {
        float xv = Yl[nl * IN_CH + kk];
        float4 wA = *(const float4*)&W1l[kk * HID + ch0];
        float4 wB = *(const float4*)&W1l[kk * HID + ch0 + 4];
        a0 += xv * wA.x; a1 += xv * wA.y; a2 += xv * wA.z; a3 += xv * wA.w;
        a4 += xv * wB.x; a5 += xv * wB.y; a6 += xv * wB.z; a7 += xv * wB.w;
    }
    float* hp = &H1l[nl * HID + ch0];
    hp[0] = fmaxf(a0, 0.f); hp[1] = fmaxf(a1, 0.f);
    hp[2] = fmaxf(a2, 0.f); hp[3] = fmaxf(a3, 0.f);
    hp[4] = fmaxf(a4, 0.f); hp[5] = fmaxf(a5, 0.f);
    hp[6] = fmaxf(a6, 0.f); hp[7] = fmaxf(a7, 0.f);
    __syncthreads();
    float r0 = 0.f, r1 = 0.f, r2 = 0.f, r3 = 0.f;
    float r4 = 0.f, r5 = 0.f, r6 = 0.f, r7 = 0.f;
#pragma unroll
    for (int kk = 0; kk < HID; ++kk) {
        float hv = H1l[nl * HID + kk];
        float4 wA = *(const float4*)&W2l[kk * HID + ch0];
        float4 wB = *(const float4*)&W2l[kk * HID + ch0 + 4];
        r0 += hv * wA.x; r1 += hv * wA.y; r2 += hv * wA.z; r3 += hv * wA.w;
        r4 += hv * wB.x; r5 += hv * wB.y; r6 += hv * wB.z; r7 += hv * wB.w;
    }
    int node = node0 + nl;
    float di = dinv[node];
    uint4 o;
    o.x = packbf(r0 * di, r1 * di);
    o.y = packbf(r2 * di, r3 * di);
    o.z = packbf(r4 * di, r5 * di);
    o.w = packbf(r6 * di, r7 * di);
    *(uint4*)(Hs2 + (size_t)node * HID + ch0) = o;
}

// ---------------------------------------------------------------------------
// K5: layer-2 edge-flow gather (64 ch) + fused classifier.
// 16 groups x 16 lanes; ds_add_f32 into acc[128][65].
//   r = relu(dinv*(acc + Hs2[n]) + b2);  out[n] = sigmoid(dot(r,Wc)+bc)
// ---------------------------------------------------------------------------
__global__ __launch_bounds__(256) void gather2_flow_kernel(
        const int* __restrict__ esw, const int* __restrict__ bbase,
        const int* __restrict__ bcnt, const float* __restrict__ dinv,
        const ushort_t* __restrict__ Hs, const float* __restrict__ b,
        const float* __restrict__ Wc, const float* __restrict__ bc,
        float* __restrict__ out) {
    __shared__ float acc[NPB * ST2];
    int t = threadIdx.x;
    for (int i = t; i < NPB * ST2; i += 256) acc[i] = 0.f;
    __syncthreads();
    int k = blockIdx.x;
    int w = t >> 6, lane = t & 63;
    int q = lane >> 4, s = lane & 15;
    int G = w + 4 * q;                 // 0..15, in-wave concurrent groups spaced 4
    int beg = bbase[k], ecnt = bcnt[k];
    const uint2* H8 = (const uint2*)Hs;
    for (int i = G; i < ecnt; i += 16) {
        int u = esw[beg + i];
        int sv = u & 0x1FFFF;
        int ld = u >> 17;
        uint2 v = H8[(size_t)sv * 16 + s];
        float* ap = &acc[ld * ST2 + s * 4];
        atomicAdd(ap + 0, bflo(v.x));
        atomicAdd(ap + 1, bfhi(v.x));
        atomicAdd(ap + 2, bflo(v.y));
        atomicAdd(ap + 3, bfhi(v.y));
    }
    __syncthreads();
    // finalize: 256 threads = 128 nodes x 2 halves (32 ch each)
    int ln = t >> 1, half = t & 1;
    int node = k * NPB + ln;
    if (node >= N_NODES) return;
    float di = dinv[node];
    const float* ap = &acc[ln * ST2 + half * 32];
    float part = 0.f;
#pragma unroll
    for (int j = 0; j < 8; ++j) {
        uint2 hn = H8[(size_t)node * 16 + half * 8 + j];
        float4 bb = ((const float4*)b)[half * 8 + j];
        float4 wc = ((const float4*)Wc)[half * 8 + j];
        float r0 = fmaxf(di * (ap[j * 4 + 0] + bflo(hn.x)) + bb.x, 0.f);
        float r1 = fmaxf(di * (ap[j * 4 + 1] + bfhi(hn.x)) + bb.y, 0.f);
        float r2 = fmaxf(di * (ap[j * 4 + 2] + bflo(hn.y)) + bb.z, 0.f);
        float r3 = fmaxf(di * (ap[j * 4 + 3] + bfhi(hn.y)) + bb.w, 0.f);
        part += r0 * wc.x + r1 * wc.y + r2 * wc.z + r3 * wc.w;
    }
    float v = part + __shfl_xor(part, 1, 64);
    if (half == 0) out[node] = 1.0f / (1.0f + expf(-(v + bc[0])));
}

// ---------------------------------------------------------------------------
extern "C" void kernel_launch(void* const* d_in, const int* in_sizes, int n_in,
                              void* d_out, int out_size, void* d_ws, size_t ws_size,
                              hipStream_t stream) {
    const float* x  = (const float*)d_in[0];
    const int* ei   = (const int*)d_in[1];
    const float* W1 = (const float*)d_in[2];
    const float* b1 = (const float*)d_in[3];
    const float* W2 = (const float*)d_in[4];
    const float* b2 = (const float*)d_in[5];
    const float* Wc = (const float*)d_in[6];
    const float* bc = (const float*)d_in[7];
    float* out = (float*)d_out;

    const int* src = ei;
    const int* dst = ei + N_EDGES;

    // Workspace: gsw[NBK*CAP] | esw[E] | gcursor[1024] | bbase[1024] | bcnt[1024] |
    //            dinv[N] | Xs[N*32] bf16 | y[N*32] bf16 | Hs2[N*64] bf16
    int*   gsw    = (int*)d_ws;
    int*   esw    = gsw + (size_t)NBK * CAP;
    int*   gcursor= esw + N_EDGES;
    int*   bbase  = gcursor + 1024;
    int*   bcnt   = bbase + 1024;
    float* dinv   = (float*)(bcnt + 1024);
    ushort_t* Xs  = (ushort_t*)(dinv + N_NODES);
    ushort_t* y   = Xs + (size_t)N_NODES * IN_CH;
    ushort_t* Hs2 = y + (size_t)N_NODES * IN_CH;

    int node32 = N_NODES / 32;   // 3125

    // ---- CSR build: bucket = 128 dsts, tile-sorted within bucket ----
    hipMemsetAsync(gcursor, 0, NBK * sizeof(int), stream);
    partition_kernel<<<PBLOCKS, 256, 0, stream>>>(src, dst, gcursor, gsw);
    bucket_place_kernel<<<NBK, 1024, 0, stream>>>(gsw, gcursor, x,
                                                  bbase, bcnt, dinv, esw, Xs);

    // ---- layer 1: edge-flow gather of Xs, fused dense W1+relu+W2 ----
    gather1_flow_kernel<<<NBK, 256, 0, stream>>>(esw, bbase, bcnt, dinv, Xs, y);
    dense12_kernel<<<node32, 256, 0, stream>>>(y, W1, b1, W2, dinv, Hs2);

    // ---- layer 2: edge-flow gather + fused classifier ----
    gather2_flow_kernel<<<NBK, 256, 0, stream>>>(esw, bbase, bcnt, dinv, Hs2,
                                                 b2, Wc, bc, out);
}

// Round 14
// 252.535 us; speedup vs baseline: 8.3056x; 8.3056x over previous
//
#include <hip/hip_runtime.h>
#include <math.h>

#define N_NODES 100000
#define N_EDGES 3200000
#define IN_CH 32
#define HID 64
#define BW 512                               // dst nodes per bucket
#define NB ((N_NODES + BW - 1) / BW)         // 196 buckets
#define CAP 17408                            // fixed capacity (mean 16327 + >6 sigma)
#define K3_CHUNK 4096                        // edges per partition block
#define K3_BLOCKS ((N_EDGES + K3_CHUNK - 1) / K3_CHUNK)   // 782

typedef unsigned short ushort_t;
typedef unsigned long long u64_t;

// ---------------- bf16 helpers ----------------
__device__ __forceinline__ float bflo(unsigned u) { return __uint_as_float(u << 16); }
__device__ __forceinline__ float bfhi(unsigned u) { return __uint_as_float(u & 0xffff0000u); }
__device__ __forceinline__ unsigned packbf(float a, float b) {
    unsigned ua = __float_as_uint(a); ua += 0x7fffu + ((ua >> 16) & 1u);
    unsigned ub = __float_as_uint(b); ub += 0x7fffu + ((ub >> 16) & 1u);
    return (ua >> 16) | (ub & 0xffff0000u);
}

// ---------------------------------------------------------------------------
// K1: partition edges into fixed-capacity bucket regions; counts -> gcursor.
// dst chunk cached in LDS during hist pass; scatter re-reads it from LDS.
// Payload: u = src | local_dst<<17
// ---------------------------------------------------------------------------
__global__ void partition_kernel(const int* __restrict__ src, const int* __restrict__ dst,
                                 int* __restrict__ gcursor, int* __restrict__ gsw) {
    __shared__ int h[NB], lbase[NB], lcur[NB];
    __shared__ int4 dcache[K3_CHUNK / 4];    // 16 KB
    int t = threadIdx.x;
    for (int i = t; i < NB; i += 256) { h[i] = 0; lcur[i] = 0; }
    __syncthreads();
    const int4* d4 = (const int4*)dst;
    const int4* s4 = (const int4*)src;
    int i0 = blockIdx.x * (K3_CHUNK / 4) + t;
#pragma unroll
    for (int j = 0; j < K3_CHUNK / 1024; ++j) {
        int i4 = i0 + j * 256;
        if (i4 < N_EDGES / 4) {
            int4 d = d4[i4];
            dcache[t + j * 256] = d;
            atomicAdd(&h[d.x >> 9], 1);
            atomicAdd(&h[d.y >> 9], 1);
            atomicAdd(&h[d.z >> 9], 1);
            atomicAdd(&h[d.w >> 9], 1);
        }
    }
    __syncthreads();
    for (int i = t; i < NB; i += 256)
        lbase[i] = h[i] ? atomicAdd(&gcursor[i], h[i]) : 0;
    __syncthreads();
#pragma unroll
    for (int j = 0; j < K3_CHUNK / 1024; ++j) {
        int i4 = i0 + j * 256;
        if (i4 < N_EDGES / 4) {
            int4 d = dcache[t + j * 256];
            int4 s = s4[i4];
            int b, r, idx;
            b = d.x >> 9; r = atomicAdd(&lcur[b], 1); idx = lbase[b] + r;
            if (idx < CAP) gsw[(size_t)b * CAP + idx] = s.x | ((d.x & (BW - 1)) << 17);
            b = d.y >> 9; r = atomicAdd(&lcur[b], 1); idx = lbase[b] + r;
            if (idx < CAP) gsw[(size_t)b * CAP + idx] = s.y | ((d.y & (BW - 1)) << 17);
            b = d.z >> 9; r = atomicAdd(&lcur[b], 1); idx = lbase[b] + r;
            if (idx < CAP) gsw[(size_t)b * CAP + idx] = s.z | ((d.z & (BW - 1)) << 17);
            b = d.w >> 9; r = atomicAdd(&lcur[b], 1); idx = lbase[b] + r;
            if (idx < CAP) gsw[(size_t)b * CAP + idx] = s.w | ((d.w & (BW - 1)) << 17);
        }
    }
}

// ---------------------------------------------------------------------------
// K2: per-bucket exact CSR placement (rowptr, dinv, compact esw=src)
//     + fused bucket-prefix reduce + fused Xs = X*dinv bf16 write.
// ---------------------------------------------------------------------------
__global__ __launch_bounds__(1024) void bucket_place_kernel(
        const int* __restrict__ gsw, const int* __restrict__ gcursor,
        const float* __restrict__ X,
        int* __restrict__ rowptr, float* __restrict__ dinv, int* __restrict__ esw,
        ushort_t* __restrict__ Xs) {
    __shared__ int cnt[BW], exc[BW], cur[BW];
    __shared__ int sa[BW], sb[BW];
    __shared__ int bsum[256];
    int t = threadIdx.x;
    int k = blockIdx.x;
    int d0 = k * BW;
    if (t < BW) { cnt[t] = 0; cur[t] = 0; }
    if (t < 256) bsum[t] = (t < k && t < NB) ? gcursor[t] : 0;
    __syncthreads();
    for (int off = 128; off > 0; off >>= 1) {
        if (t < off) bsum[t] += bsum[t + off];
        __syncthreads();
    }
    int cbase = bsum[0];
    int total = gcursor[k];
    if (total > CAP) total = CAP;
    const int* reg = gsw + (size_t)k * CAP;
    for (int i = t; i < total; i += 1024)
        atomicAdd(&cnt[reg[i] >> 17], 1);
    __syncthreads();
    if (t < BW) sa[t] = cnt[t];
    __syncthreads();
    int* pa = sa; int* pb = sb;
    for (int off = 1; off < BW; off <<= 1) {
        if (t < BW) {
            int add = (t >= off) ? pa[t - off] : 0;
            pb[t] = pa[t] + add;
        }
        __syncthreads();
        int* tmp = pa; pa = pb; pb = tmp;
    }
    if (t < BW) {
        int e_x = pa[t] - cnt[t];
        exc[t] = e_x;
        int d = d0 + t;
        if (d < N_NODES) {
            rowptr[d] = cbase + e_x;
            dinv[d] = rsqrtf((float)cnt[t] + 1.0f);
        }
    }
    if (k == NB - 1 && t == 0) rowptr[N_NODES] = N_EDGES;
    __syncthreads();
    for (int i = t; i < total; i += 1024) {
        int u = reg[i];
        int ld = u >> 17;
        int r = atomicAdd(&cur[ld], 1);
        esw[cbase + exc[ld] + r] = u & 0x1FFFF;
    }
    const float4* X4 = (const float4*)X;
    for (int i = t; i < BW * 8; i += 1024) {
        int nl = i >> 3;
        int node = d0 + nl;
        if (node >= N_NODES) break;
        float di = rsqrtf((float)cnt[nl] + 1.0f);
        float4 v = X4[(size_t)node * 8 + (i & 7)];
        u64_t o = ((u64_t)packbf(v.z * di, v.w * di) << 32) | packbf(v.x * di, v.y * di);
        *(u64_t*)((uint2*)Xs + (size_t)node * 8 + (i & 7)) = o;
    }
}

// ---------------------------------------------------------------------------
// K3: layer-1 gather over 64B bf16 Xs rows, unroll-4.
//   y[d] = dinv[d] * (sum_e Xs[src_e] + Xs[d])   -> bf16 [N][32]
// ---------------------------------------------------------------------------
__global__ void gather_x_kernel(const int* __restrict__ esw, const int* __restrict__ rowptr,
                                const float* __restrict__ dinv, const ushort_t* __restrict__ Xs,
                                ushort_t* __restrict__ y) {
    int t = threadIdx.x;
    int node = blockIdx.x * 4 + (t >> 6);
    int lane = t & 63;
    int g = lane >> 3, s = lane & 7;
    int beg = rowptr[node], end = rowptr[node + 1];
    const uint2* H8 = (const uint2*)Xs;
    float4 acc = make_float4(0.f, 0.f, 0.f, 0.f);
    int i = beg + g;
    for (; i + 24 < end; i += 32) {
        int e0 = esw[i];
        int e1 = esw[i + 8];
        int e2 = esw[i + 16];
        int e3 = esw[i + 24];
        uint2 v0 = H8[(size_t)e0 * 8 + s];
        uint2 v1 = H8[(size_t)e1 * 8 + s];
        uint2 v2 = H8[(size_t)e2 * 8 + s];
        uint2 v3 = H8[(size_t)e3 * 8 + s];
        acc.x += (bflo(v0.x) + bflo(v1.x)) + (bflo(v2.x) + bflo(v3.x));
        acc.y += (bfhi(v0.x) + bfhi(v1.x)) + (bfhi(v2.x) + bfhi(v3.x));
        acc.z += (bflo(v0.y) + bflo(v1.y)) + (bflo(v2.y) + bflo(v3.y));
        acc.w += (bfhi(v0.y) + bfhi(v1.y)) + (bfhi(v2.y) + bfhi(v3.y));
    }
    for (; i < end; i += 8) {
        int e0 = esw[i];
        uint2 v0 = H8[(size_t)e0 * 8 + s];
        acc.x += bflo(v0.x);
        acc.y += bfhi(v0.x);
        acc.z += bflo(v0.y);
        acc.w += bfhi(v0.y);
    }
    acc.x += __shfl_xor(acc.x, 8, 64);  acc.y += __shfl_xor(acc.y, 8, 64);
    acc.z += __shfl_xor(acc.z, 8, 64);  acc.w += __shfl_xor(acc.w, 8, 64);
    acc.x += __shfl_xor(acc.x, 16, 64); acc.y += __shfl_xor(acc.y, 16, 64);
    acc.z += __shfl_xor(acc.z, 16, 64); acc.w += __shfl_xor(acc.w, 16, 64);
    acc.x += __shfl_xor(acc.x, 32, 64); acc.y += __shfl_xor(acc.y, 32, 64);
    acc.z += __shfl_xor(acc.z, 32, 64); acc.w += __shfl_xor(acc.w, 32, 64);

    if (g == 0) {
        uint2 hn = H8[(size_t)node * 8 + s];
        float di = dinv[node];
        float rx = di * (acc.x + bflo(hn.x));
        float ry = di * (acc.y + bfhi(hn.x));
        float rz = di * (acc.z + bflo(hn.y));
        float rw = di * (acc.w + bfhi(hn.y));
        u64_t o = ((u64_t)packbf(rz, rw) << 32) | packbf(rx, ry);
        *(u64_t*)((uint2*)y + (size_t)node * 8 + s) = o;
    }
}

// ---------------------------------------------------------------------------
// K4: fused dense: H1 = relu(y@W1 + b1); Hs2 = (H1@W2)*dinv -> bf16 [N][64]
// ---------------------------------------------------------------------------
__global__ __launch_bounds__(256) void dense12_kernel(
        const ushort_t* __restrict__ ybf, const float* __restrict__ W1,
        const float* __restrict__ b1, const float* __restrict__ W2,
        const float* __restrict__ dinv, ushort_t* __restrict__ Hs2) {
    __shared__ float W1l[IN_CH * HID];
    __shared__ float W2l[HID * HID];
    __shared__ float Yl[32 * IN_CH];
    __shared__ float H1l[32 * HID];
    int t = threadIdx.x;
    int node0 = blockIdx.x * 32;
    for (int i = t; i < IN_CH * HID / 4; i += 256) ((float4*)W1l)[i] = ((const float4*)W1)[i];
    for (int i = t; i < HID * HID / 4; i += 256) ((float4*)W2l)[i] = ((const float4*)W2)[i];
    {
        uint2 v = ((const uint2*)ybf)[(size_t)node0 * 8 + t];
        int nl = t >> 3, ci = t & 7;
        Yl[nl * IN_CH + ci * 4 + 0] = bflo(v.x);
        Yl[nl * IN_CH + ci * 4 + 1] = bfhi(v.x);
        Yl[nl * IN_CH + ci * 4 + 2] = bflo(v.y);
        Yl[nl * IN_CH + ci * 4 + 3] = bfhi(v.y);
    }
    __syncthreads();
    int nl = t >> 3;
    int c8 = t & 7;
    int ch0 = c8 * 8;
    float4 bA = ((const float4*)b1)[c8 * 2];
    float4 bB = ((const float4*)b1)[c8 * 2 + 1];
    float a0 = bA.x, a1 = bA.y, a2 = bA.z, a3 = bA.w;
    float a4 = bB.x, a5 = bB.y, a6 = bB.z, a7 = bB.w;
#pragma unroll
    for (int kk = 0; kk < IN_CH; ++kk) {
        float xv = Yl[nl * IN_CH + kk];
        float4 wA = *(const float4*)&W1l[kk * HID + ch0];
        float4 wB = *(const float4*)&W1l[kk * HID + ch0 + 4];
        a0 += xv * wA.x; a1 += xv * wA.y; a2 += xv * wA.z; a3 += xv * wA.w;
        a4 += xv * wB.x; a5 += xv * wB.y; a6 += xv * wB.z; a7 += xv * wB.w;
    }
    float* hp = &H1l[nl * HID + ch0];
    hp[0] = fmaxf(a0, 0.f); hp[1] = fmaxf(a1, 0.f);
    hp[2] = fmaxf(a2, 0.f); hp[3] = fmaxf(a3, 0.f);
    hp[4] = fmaxf(a4, 0.f); hp[5] = fmaxf(a5, 0.f);
    hp[6] = fmaxf(a6, 0.f); hp[7] = fmaxf(a7, 0.f);
    __syncthreads();
    float r0 = 0.f, r1 = 0.f, r2 = 0.f, r3 = 0.f;
    float r4 = 0.f, r5 = 0.f, r6 = 0.f, r7 = 0.f;
#pragma unroll
    for (int kk = 0; kk < HID; ++kk) {
        float hv = H1l[nl * HID + kk];
        float4 wA = *(const float4*)&W2l[kk * HID + ch0];
        float4 wB = *(const float4*)&W2l[kk * HID + ch0 + 4];
        r0 += hv * wA.x; r1 += hv * wA.y; r2 += hv * wA.z; r3 += hv * wA.w;
        r4 += hv * wB.x; r5 += hv * wB.y; r6 += hv * wB.z; r7 += hv * wB.w;
    }
    int node = node0 + nl;
    float di = dinv[node];
    uint4 o;
    o.x = packbf(r0 * di, r1 * di);
    o.y = packbf(r2 * di, r3 * di);
    o.z = packbf(r4 * di, r5 * di);
    o.w = packbf(r6 * di, r7 * di);
    *(uint4*)(Hs2 + (size_t)node * HID + ch0) = o;
}

// ---------------------------------------------------------------------------
// K5: layer-2 gather over 128B bf16 Hs2 rows + fused classifier.
// 8 edge-groups x 8 lanes x uint4; unroll-4 (4 row loads in flight).
// ---------------------------------------------------------------------------
__global__ void gather_cls_kernel(const int* __restrict__ esw, const int* __restrict__ rowptr,
                                  const float* __restrict__ dinv, const ushort_t* __restrict__ Hs,
                                  const float* __restrict__ b,
                                  const float* __restrict__ Wc, const float* __restrict__ bc,
                                  float* __restrict__ out) {
    int t = threadIdx.x;
    int node = blockIdx.x * 4 + (t >> 6);
    int lane = t & 63;
    int g = lane >> 3, s = lane & 7;
    int beg = rowptr[node], end = rowptr[node + 1];
    int cnt = end - beg;
    const uint4* H16 = (const uint4*)Hs;    // node row = 8 uint4 (64 ch)
    float a0 = 0.f, a1 = 0.f, a2 = 0.f, a3 = 0.f;
    float a4 = 0.f, a5 = 0.f, a6 = 0.f, a7 = 0.f;
    int i = g;
    for (; i + 24 < cnt; i += 32) {
        int e0 = esw[beg + i];
        int e1 = esw[beg + i + 8];
        int e2 = esw[beg + i + 16];
        int e3 = esw[beg + i + 24];
        uint4 v0 = H16[(size_t)e0 * 8 + s];
        uint4 v1 = H16[(size_t)e1 * 8 + s];
        uint4 v2 = H16[(size_t)e2 * 8 + s];
        uint4 v3 = H16[(size_t)e3 * 8 + s];
        a0 += (bflo(v0.x) + bflo(v1.x)) + (bflo(v2.x) + bflo(v3.x));
        a1 += (bfhi(v0.x) + bfhi(v1.x)) + (bfhi(v2.x) + bfhi(v3.x));
        a2 += (bflo(v0.y) + bflo(v1.y)) + (bflo(v2.y) + bflo(v3.y));
        a3 += (bfhi(v0.y) + bfhi(v1.y)) + (bfhi(v2.y) + bfhi(v3.y));
        a4 += (bflo(v0.z) + bflo(v1.z)) + (bflo(v2.z) + bflo(v3.z));
        a5 += (bfhi(v0.z) + bfhi(v1.z)) + (bfhi(v2.z) + bfhi(v3.z));
        a6 += (bflo(v0.w) + bflo(v1.w)) + (bflo(v2.w) + bflo(v3.w));
        a7 += (bfhi(v0.w) + bfhi(v1.w)) + (bfhi(v2.w) + bfhi(v3.w));
    }
    for (; i < cnt; i += 8) {
        int e0 = esw[beg + i];
        uint4 v0 = H16[(size_t)e0 * 8 + s];
        a0 += bflo(v0.x); a1 += bfhi(v0.x);
        a2 += bflo(v0.y); a3 += bfhi(v0.y);
        a4 += bflo(v0.z); a5 += bfhi(v0.z);
        a6 += bflo(v0.w); a7 += bfhi(v0.w);
    }
#define RED8(m) \
    a0 += __shfl_xor(a0, m, 64); a1 += __shfl_xor(a1, m, 64); \
    a2 += __shfl_xor(a2, m, 64); a3 += __shfl_xor(a3, m, 64); \
    a4 += __shfl_xor(a4, m, 64); a5 += __shfl_xor(a5, m, 64); \
    a6 += __shfl_xor(a6, m, 64); a7 += __shfl_xor(a7, m, 64);
    RED8(8) RED8(16) RED8(32)
#undef RED8

    uint4 hn = H16[(size_t)node * 8 + s];
    float di = dinv[node];
    float4 bA = ((const float4*)b)[s * 2];
    float4 bB = ((const float4*)b)[s * 2 + 1];
    float r0 = fmaxf(di * (a0 + bflo(hn.x)) + bA.x, 0.f);
    float r1 = fmaxf(di * (a1 + bfhi(hn.x)) + bA.y, 0.f);
    float r2 = fmaxf(di * (a2 + bflo(hn.y)) + bA.z, 0.f);
    float r3 = fmaxf(di * (a3 + bfhi(hn.y)) + bA.w, 0.f);
    float r4 = fmaxf(di * (a4 + bflo(hn.z)) + bB.x, 0.f);
    float r5 = fmaxf(di * (a5 + bfhi(hn.z)) + bB.y, 0.f);
    float r6 = fmaxf(di * (a6 + bflo(hn.w)) + bB.z, 0.f);
    float r7 = fmaxf(di * (a7 + bfhi(hn.w)) + bB.w, 0.f);

    float4 wA = ((const float4*)Wc)[s * 2];
    float4 wB = ((const float4*)Wc)[s * 2 + 1];
    float v = r0 * wA.x + r1 * wA.y + r2 * wA.z + r3 * wA.w
            + r4 * wB.x + r5 * wB.y + r6 * wB.z + r7 * wB.w;
    v += __shfl_xor(v, 1, 64);
    v += __shfl_xor(v, 2, 64);
    v += __shfl_xor(v, 4, 64);
    if (lane == 0) out[node] = 1.0f / (1.0f + expf(-(v + bc[0])));
}

// ---------------------------------------------------------------------------
extern "C" void kernel_launch(void* const* d_in, const int* in_sizes, int n_in,
                              void* d_out, int out_size, void* d_ws, size_t ws_size,
                              hipStream_t stream) {
    const float* x  = (const float*)d_in[0];
    const int* ei   = (const int*)d_in[1];
    const float* W1 = (const float*)d_in[2];
    const float* b1 = (const float*)d_in[3];
    const float* W2 = (const float*)d_in[4];
    const float* b2 = (const float*)d_in[5];
    const float* Wc = (const float*)d_in[6];
    const float* bc = (const float*)d_in[7];
    float* out = (float*)d_out;

    const int* src = ei;
    const int* dst = ei + N_EDGES;

    int*   gsw    = (int*)d_ws;
    int*   esw    = gsw + (size_t)NB * CAP;
    int*   rowptr = esw + N_EDGES;
    float* dinv   = (float*)(rowptr + N_NODES + 8);
    int*   gcursor= (int*)(dinv + N_NODES);
    ushort_t* Xs  = (ushort_t*)(gcursor + 512);
    ushort_t* y   = Xs + (size_t)N_NODES * IN_CH;
    ushort_t* Hs2 = y + (size_t)N_NODES * IN_CH;

    int node32 = N_NODES / 32;   // 3125
    int node4  = N_NODES / 4;    // 25000

    hipMemsetAsync(gcursor, 0, NB * sizeof(int), stream);
    partition_kernel<<<K3_BLOCKS, 256, 0, stream>>>(src, dst, gcursor, gsw);
    bucket_place_kernel<<<NB, 1024, 0, stream>>>(gsw, gcursor, x,
                                                 rowptr, dinv, esw, Xs);

    gather_x_kernel<<<node4, 256, 0, stream>>>(esw, rowptr, dinv, Xs, y);
    dense12_kernel<<<node32, 256, 0, stream>>>(y, W1, b1, W2, dinv, Hs2);

    gather_cls_kernel<<<node4, 256, 0, stream>>>(esw, rowptr, dinv, Hs2, b2, Wc, bc, out);
}